// Round 9
// baseline (649.857 us; speedup 1.0000x reference)
//
#include <hip/hip_runtime.h>
#include <hip/hip_cooperative_groups.h>

namespace cg = cooperative_groups;

#define N_NODES 50000
#define N_EDGES 800000
// D_IN = D_HID = 128, D_OUT = 2

typedef __bf16 bf16_8 __attribute__((ext_vector_type(8)));
typedef float  f32_4  __attribute__((ext_vector_type(4)));
#define LDA 264   // padded LDS row (bf16) for the GEMM A-tile

// ---------------- workspace layout (bytes) ----------------
// deg_p    int[50000*16]   @ 0          (64B-padded atomic counters)
// edge_pos int[800000]     @ 3200000
// rowptr   int[50000]      @ 6400000    (block-partial exclusive scan)
// degc     int[50000]      @ 6600192
// bsum     int[256]        @ 6800384    (RAW per-block sums; prefix computed locally)
// csr      int[800000]     @ 6801408
// xb       bf16[50000*128] @ 10001408   (dense bf16 x — gather working set)
// aggb     bf16[50000*128] @ 22801408
// y        f32[50000*2]    @ 35601408
// z        f32[50000*2]    @ 36001408
// Wt       bf16[128*256]   @ 36401408   ([n][k], k<128 = W1l (agg), else W1r (self))

__global__ __launch_bounds__(256, 4) void mega_kernel(
    const float* __restrict__ x, const int* __restrict__ src,
    const int* __restrict__ dst,
    const float* __restrict__ W1l, const float* __restrict__ W1r,
    const float* __restrict__ b1,
    const float* __restrict__ W2l, const float* __restrict__ W2r,
    const float* __restrict__ b2, float* __restrict__ out,
    int* __restrict__ deg_p, int* __restrict__ edge_pos,
    int* __restrict__ rowptr, int* __restrict__ degc, int* __restrict__ bsum,
    int* __restrict__ csr, __bf16* __restrict__ xb, __bf16* __restrict__ aggb,
    float* __restrict__ y, float* __restrict__ z, __bf16* __restrict__ Wt)
{
    cg::grid_group grid = cg::this_grid();
    __shared__ char lds[64 * LDA * 2];        // 33792 B, reused across phases
    int*    s_scan = (int*)lds;               // [0, 1024)
    int*    s_boff = (int*)(lds + 1024);      // [1024, 2048) — survives within a phase
    __bf16* As     = (__bf16*)lds;            // full buffer (gemm phase)

    const int tid = threadIdx.x;
    const int g   = blockIdx.x * 256 + tid;
    const int G   = gridDim.x * 256;

    // ---------------- P0: prep (x->bf16, Wt build, zero deg_p) ----------------
    for (int t = g; t < 800000; t += G) {     // 50000 rows x 16 chunks
        int node = t >> 4, c8 = t & 15;
        const float4* xp = (const float4*)(x + node * 128 + c8 * 8);
        float4 v0 = xp[0], v1 = xp[1];
        bf16_8 o;
        o[0] = (__bf16)v0.x; o[1] = (__bf16)v0.y; o[2] = (__bf16)v0.z; o[3] = (__bf16)v0.w;
        o[4] = (__bf16)v1.x; o[5] = (__bf16)v1.y; o[6] = (__bf16)v1.z; o[7] = (__bf16)v1.w;
        *(bf16_8*)(xb + t * 8) = o;
    }
    for (int t = g; t < 32768; t += G) {
        int n = t >> 8, k = t & 255;
        float v = (k < 128) ? W1l[n * 128 + k] : W1r[n * 128 + (k - 128)];
        Wt[t] = (__bf16)v;
    }
    for (int t = g; t < 200000; t += G)
        ((int4*)deg_p)[t] = make_int4(0, 0, 0, 0);
    grid.sync();

    // ---------------- P1: degree count + per-edge slot ----------------
    for (int e = g; e < N_EDGES; e += G)
        edge_pos[e] = atomicAdd(&deg_p[dst[e] * 16], 1);
    grid.sync();

    // ---------------- P2: per-256-node-block exclusive scan ----------------
    for (int vb = blockIdx.x; vb < 196; vb += gridDim.x) {
        int i = vb * 256 + tid;
        int v = (i < N_NODES) ? deg_p[i * 16] : 0;
        if (i < N_NODES) degc[i] = v;
        s_scan[tid] = v;
        __syncthreads();
        #pragma unroll
        for (int off = 1; off < 256; off <<= 1) {
            int t2 = (tid >= off) ? s_scan[tid - off] : 0;
            __syncthreads();
            s_scan[tid] += t2;
            __syncthreads();
        }
        if (i < N_NODES) rowptr[i] = s_scan[tid] - v;
        if (tid == 255) bsum[vb] = s_scan[255];
        __syncthreads();
    }
    grid.sync();

    // ---- local exclusive scan of bsum[196] into s_boff (block-local) ----
    {
        int v = (tid < 196) ? bsum[tid] : 0;
        s_scan[tid] = v;
        __syncthreads();
        #pragma unroll
        for (int off = 1; off < 256; off <<= 1) {
            int t2 = (tid >= off) ? s_scan[tid - off] : 0;
            __syncthreads();
            s_scan[tid] += t2;
            __syncthreads();
        }
        s_boff[tid] = s_scan[tid] - v;
        __syncthreads();
    }

    // ---------------- P3: fill csr (pure scatter, no atomics) ----------------
    for (int e = g; e < N_EDGES; e += G) {
        int d = dst[e];
        csr[rowptr[d] + s_boff[d >> 8] + edge_pos[e]] = src[e];
    }
    grid.sync();

    // ---------------- P4: pull-based mean-agg (s_boff still valid) ----------------
    for (int t = g; t < 800000; t += G) {
        int node = t >> 4, c8 = t & 15;
        int beg = rowptr[node] + s_boff[node >> 8];
        int n = degc[node];
        float acc[8] = {};
        int j = 0;
        for (; j + 2 <= n; j += 2) {
            int s0 = csr[beg + j], s1 = csr[beg + j + 1];
            bf16_8 v0 = *(const bf16_8*)(xb + s0 * 128 + c8 * 8);
            bf16_8 v1 = *(const bf16_8*)(xb + s1 * 128 + c8 * 8);
            #pragma unroll
            for (int u = 0; u < 8; ++u) acc[u] += (float)v0[u] + (float)v1[u];
        }
        if (j < n) {
            int s0 = csr[beg + j];
            bf16_8 v0 = *(const bf16_8*)(xb + s0 * 128 + c8 * 8);
            #pragma unroll
            for (int u = 0; u < 8; ++u) acc[u] += (float)v0[u];
        }
        float inv = 1.0f / fmaxf((float)n, 1.0f);
        bf16_8 o;
        #pragma unroll
        for (int u = 0; u < 8; ++u) o[u] = (__bf16)(acc[u] * inv);
        *(bf16_8*)(aggb + t * 8) = o;
    }
    grid.sync();

    // ---------------- P5: MFMA GEMM + fused layer-2 epilogue ----------------
    for (int tb = blockIdx.x; tb < 782; tb += gridDim.x) {
        const int i0 = tb * 64;
        __syncthreads();   // As reuse guard (also vs s_boff use above)
        #pragma unroll
        for (int s = 0; s < 8; ++s) {
            int v = tid + s * 256;            // 0..2047 = 64 rows x 32 chunks
            int row = v >> 5, c8 = v & 31;
            int gi = i0 + row;
            bf16_8 val = {};
            if (gi < N_NODES) {
                val = (c8 < 16) ? *(const bf16_8*)(aggb + gi * 128 + c8 * 8)
                                : *(const bf16_8*)(xb + gi * 128 + (c8 - 16) * 8);
            }
            *(bf16_8*)(&As[row * LDA + c8 * 8]) = val;
        }
        __syncthreads();

        const int wv = tid >> 6, lane = tid & 63;
        const int m0 = wv * 16;
        const int mr = lane & 15, q = lane >> 4;

        f32_4 acc[8];
        #pragma unroll
        for (int nt = 0; nt < 8; ++nt) acc[nt] = (f32_4){0.f, 0.f, 0.f, 0.f};

        #pragma unroll
        for (int ks = 0; ks < 8; ++ks) {
            bf16_8 a = *(const bf16_8*)(&As[(m0 + mr) * LDA + ks * 32 + q * 8]);
            #pragma unroll
            for (int nt = 0; nt < 8; ++nt) {
                bf16_8 b = *(const bf16_8*)(Wt + (nt * 16 + mr) * 256 + ks * 32 + q * 8);
                acc[nt] = __builtin_amdgcn_mfma_f32_16x16x32_bf16(a, b, acc[nt], 0, 0, 0);
            }
        }

        float py0[4] = {}, py1[4] = {}, pz0[4] = {}, pz1[4] = {};
        #pragma unroll
        for (int nt = 0; nt < 8; ++nt) {
            int col = nt * 16 + mr;
            float bb  = b1[col];
            float wl0 = W2l[col], wl1 = W2l[128 + col];
            float wr0 = W2r[col], wr1 = W2r[128 + col];
            #pragma unroll
            for (int r = 0; r < 4; ++r) {
                float hv = fmaxf(acc[nt][r] + bb, 0.f);
                py0[r] += hv * wl0; py1[r] += hv * wl1;
                pz0[r] += hv * wr0; pz1[r] += hv * wr1;
            }
        }
        #pragma unroll
        for (int off = 1; off < 16; off <<= 1) {
            #pragma unroll
            for (int r = 0; r < 4; ++r) {
                py0[r] += __shfl_xor(py0[r], off);
                py1[r] += __shfl_xor(py1[r], off);
                pz0[r] += __shfl_xor(pz0[r], off);
                pz1[r] += __shfl_xor(pz1[r], off);
            }
        }
        if (mr < 4) {
            int r = mr;
            int row = i0 + m0 + q * 4 + r;
            if (row < N_NODES) {
                ((float2*)y)[row] = make_float2(py0[r], py1[r]);
                ((float2*)z)[row] = make_float2(pz0[r], pz1[r]);
            }
        }
    }
    grid.sync();

    // ---- recompute s_boff (As clobbered it) ----
    {
        int v = (tid < 196) ? bsum[tid] : 0;
        s_scan[tid] = v;
        __syncthreads();
        #pragma unroll
        for (int off = 1; off < 256; off <<= 1) {
            int t2 = (tid >= off) ? s_scan[tid - off] : 0;
            __syncthreads();
            s_scan[tid] += t2;
            __syncthreads();
        }
        s_boff[tid] = s_scan[tid] - v;
        __syncthreads();
    }

    // ---------------- P6: final = csr-mean(y) + z + b2 ----------------
    for (int t = g; t < 2 * N_NODES; t += G) {
        int node = t >> 1, c = t & 1;
        int beg = rowptr[node] + s_boff[node >> 8];
        int n = degc[node];
        float acc = 0.f;
        for (int j = 0; j < n; ++j) acc += y[csr[beg + j] * 2 + c];
        out[t] = acc / fmaxf((float)n, 1.0f) + z[t] + b2[c];
    }
}

extern "C" void kernel_launch(void* const* d_in, const int* in_sizes, int n_in,
                              void* d_out, int out_size, void* d_ws, size_t ws_size,
                              hipStream_t stream) {
    const float* x   = (const float*)d_in[0];
    const int*   ei  = (const int*)  d_in[1];
    const float* W1l = (const float*)d_in[2];
    const float* W1r = (const float*)d_in[3];
    const float* b1  = (const float*)d_in[4];
    const float* W2l = (const float*)d_in[5];
    const float* W2r = (const float*)d_in[6];
    const float* b2  = (const float*)d_in[7];
    float* out = (float*)d_out;
    const int* src = ei;
    const int* dst = ei + N_EDGES;

    char* ws = (char*)d_ws;
    int*    deg_p    = (int*)   (ws + 0);
    int*    edge_pos = (int*)   (ws + 3200000);
    int*    rowptr   = (int*)   (ws + 6400000);
    int*    degc     = (int*)   (ws + 6600192);
    int*    bsum     = (int*)   (ws + 6800384);
    int*    csr      = (int*)   (ws + 6801408);
    __bf16* xb       = (__bf16*)(ws + 10001408);
    __bf16* aggb     = (__bf16*)(ws + 22801408);
    float*  yb       = (float*) (ws + 35601408);
    float*  zb       = (float*) (ws + 36001408);
    __bf16* Wt       = (__bf16*)(ws + 36401408);

    // co-resident grid size: LDS 33792 B/block -> 4 blocks/CU on MI355X (256 CUs)
    int perCU = 0;
    hipOccupancyMaxActiveBlocksPerMultiprocessor(&perCU, mega_kernel, 256, 0);
    if (perCU < 1) perCU = 1;
    int nblk = perCU * 256;
    if (nblk > 1024) nblk = 1024;

    void* args[] = {
        (void*)&x, (void*)&src, (void*)&dst,
        (void*)&W1l, (void*)&W1r, (void*)&b1,
        (void*)&W2l, (void*)&W2r, (void*)&b2, (void*)&out,
        (void*)&deg_p, (void*)&edge_pos, (void*)&rowptr, (void*)&degc,
        (void*)&bsum, (void*)&csr, (void*)&xb, (void*)&aggb,
        (void*)&yb, (void*)&zb, (void*)&Wt
    };
    hipLaunchCooperativeKernel((void*)mega_kernel, dim3(nblk), dim3(256),
                               args, 0, stream);
}

// Round 10
// 208.895 us; speedup vs baseline: 3.1109x; 3.1109x over previous
//
#include <hip/hip_runtime.h>

#define N_NODES 50000
#define N_EDGES 800000
// D_IN = D_HID = 128, D_OUT = 2

typedef __bf16 bf16_8 __attribute__((ext_vector_type(8)));
typedef float  f32_4  __attribute__((ext_vector_type(4)));

// ---------------- workspace layout (bytes) ----------------
// deg_p    int[50000*16]   @ 0          (3.2MB, 64B-padded atomic counters)
// edge_pos int[800000]     @ 3200000
// rowptr   int[50000]      @ 6400000    (block-partial exclusive scan)
// degc     int[50000]      @ 6600192
// bsum     int[256]        @ 6800384    (RAW per-256-node-block sums)
// csr      int[800000]     @ 6801408
// xb       bf16[50000*128] @ 10001408   (dense bf16 x — gather working set)
// aggb     bf16[50000*128] @ 22801408
// y        f32[50000*2]    @ 35601408
// z        f32[50000*2]    @ 36001408
// Wt       bf16[128*256]   @ 36401408   ([n][k], k<128 = W1l (agg), else W1r (self))
// total ~36.5 MB

// fused: blocks 0..3124 — x->bf16 conversion AND degree-count+slot for edge t
//        (independent tasks, same index space; atomic latency hides under streaming)
//        blocks 3125..3252 — build Wt
__global__ void prep_deg_kernel(const float* __restrict__ W1l, const float* __restrict__ W1r,
                                __bf16* __restrict__ Wt, const float* __restrict__ x,
                                __bf16* __restrict__ xb, const int* __restrict__ dst,
                                int* __restrict__ deg_p, int* __restrict__ edge_pos) {
    int b = blockIdx.x;
    if (b < 3125) {
        int t = b * 256 + threadIdx.x;   // 800000
        // edge task
        int d = dst[t];
        int pos = atomicAdd(&deg_p[d * 16], 1);
        // conversion task (independent; overlaps atomic latency)
        int node = t >> 4, c8 = t & 15;
        const float4* xp = (const float4*)(x + node * 128 + c8 * 8);
        float4 v0 = xp[0], v1 = xp[1];
        bf16_8 o;
        o[0] = (__bf16)v0.x; o[1] = (__bf16)v0.y; o[2] = (__bf16)v0.z; o[3] = (__bf16)v0.w;
        o[4] = (__bf16)v1.x; o[5] = (__bf16)v1.y; o[6] = (__bf16)v1.z; o[7] = (__bf16)v1.w;
        *(bf16_8*)(xb + t * 8) = o;
        edge_pos[t] = pos;
    } else {
        int t = (b - 3125) * 256 + threadIdx.x;   // 32768
        int n = t >> 8, k = t & 255;
        float v = (k < 128) ? W1l[n * 128 + k] : W1r[n * 128 + (k - 128)];
        Wt[t] = (__bf16)v;
    }
}

// per-block exclusive scan of padded degrees; emits packed degc + RAW block sums
__global__ void scan_block_kernel(const int* __restrict__ deg_p, int* __restrict__ rowptr,
                                  int* __restrict__ degc, int* __restrict__ bsum) {
    __shared__ int s[256];
    int i = blockIdx.x * 256 + threadIdx.x;
    int v = (i < N_NODES) ? deg_p[i * 16] : 0;
    if (i < N_NODES) degc[i] = v;
    s[threadIdx.x] = v;
    __syncthreads();
    #pragma unroll
    for (int off = 1; off < 256; off <<= 1) {
        int t = (threadIdx.x >= off) ? s[threadIdx.x - off] : 0;
        __syncthreads();
        s[threadIdx.x] += t;
        __syncthreads();
    }
    if (i < N_NODES) rowptr[i] = s[threadIdx.x] - v;
    if (threadIdx.x == 255) bsum[blockIdx.x] = s[255];
}

// LDS-local exclusive scan of the 196 raw block sums -> s_boff
__device__ __forceinline__ void local_bsum_scan(const int* __restrict__ bsum,
                                                int* s_scan, int* s_boff) {
    int tid = threadIdx.x;
    int v = (tid < 196) ? bsum[tid] : 0;
    s_scan[tid] = v;
    __syncthreads();
    #pragma unroll
    for (int off = 1; off < 256; off <<= 1) {
        int t = (tid >= off) ? s_scan[tid - off] : 0;
        __syncthreads();
        s_scan[tid] += t;
        __syncthreads();
    }
    s_boff[tid] = s_scan[tid] - v;
    __syncthreads();
}

// pure scatter, no atomics
__global__ void fill_csr_kernel(const int* __restrict__ src, const int* __restrict__ dst,
                                const int* __restrict__ rowptr, const int* __restrict__ bsum,
                                const int* __restrict__ edge_pos, int* __restrict__ csr) {
    __shared__ int s_scan[256], s_boff[256];
    local_bsum_scan(bsum, s_scan, s_boff);
    int e = blockIdx.x * 256 + threadIdx.x;   // exactly 800000
    int d = dst[e];
    csr[rowptr[d] + s_boff[d >> 8] + edge_pos[e]] = src[e];
}

// pull-based mean-agg: thread = (node, 16B chunk); 800k threads, 4-way unrolled
__global__ __launch_bounds__(256) void agg_kernel(
    const int* __restrict__ rowptr, const int* __restrict__ bsum,
    const int* __restrict__ degc, const int* __restrict__ csr,
    const __bf16* __restrict__ xb, __bf16* __restrict__ aggb)
{
    __shared__ int s_scan[256], s_boff[256];
    local_bsum_scan(bsum, s_scan, s_boff);
    int t = blockIdx.x * 256 + threadIdx.x;   // exactly 50000*16
    int node = t >> 4, c8 = t & 15;
    int beg = rowptr[node] + s_boff[node >> 8], n = degc[node];
    float acc[8] = {};
    int j = 0;
    for (; j + 4 <= n; j += 4) {
        int s0 = csr[beg + j],     s1 = csr[beg + j + 1];
        int s2 = csr[beg + j + 2], s3 = csr[beg + j + 3];
        bf16_8 v0 = *(const bf16_8*)(xb + s0 * 128 + c8 * 8);
        bf16_8 v1 = *(const bf16_8*)(xb + s1 * 128 + c8 * 8);
        bf16_8 v2 = *(const bf16_8*)(xb + s2 * 128 + c8 * 8);
        bf16_8 v3 = *(const bf16_8*)(xb + s3 * 128 + c8 * 8);
        #pragma unroll
        for (int u = 0; u < 8; ++u)
            acc[u] += ((float)v0[u] + (float)v1[u]) + ((float)v2[u] + (float)v3[u]);
    }
    for (; j < n; ++j) {
        int s0 = csr[beg + j];
        bf16_8 v0 = *(const bf16_8*)(xb + s0 * 128 + c8 * 8);
        #pragma unroll
        for (int u = 0; u < 8; ++u) acc[u] += (float)v0[u];
    }
    float inv = 1.0f / fmaxf((float)n, 1.0f);
    bf16_8 o;
    #pragma unroll
    for (int u = 0; u < 8; ++u) o[u] = (__bf16)(acc[u] * inv);
    *(bf16_8*)(aggb + t * 8) = o;
}

// MFMA GEMM over [aggb | xb] vs Wt (K=256) + epilogue contracting relu(h) with W2.
#define LDA 264
__global__ __launch_bounds__(256) void gemm_fused_kernel(
    const __bf16* __restrict__ aggb, const __bf16* __restrict__ xb,
    const __bf16* __restrict__ Wt, const float* __restrict__ b1,
    const float* __restrict__ W2l, const float* __restrict__ W2r,
    float* __restrict__ y, float* __restrict__ z)
{
    __shared__ __bf16 As[64 * LDA];
    const int i0 = blockIdx.x * 64;
    const int tid = threadIdx.x;

    // stage 64 rows: cols 0-127 from aggb, 128-255 from xb
    #pragma unroll
    for (int s = 0; s < 8; ++s) {
        int v = tid + s * 256;            // 0..2047
        int row = v >> 5, c8 = v & 31;
        int gi = i0 + row;
        bf16_8 val = {};
        if (gi < N_NODES) {
            val = (c8 < 16) ? *(const bf16_8*)(aggb + gi * 128 + c8 * 8)
                            : *(const bf16_8*)(xb + gi * 128 + (c8 - 16) * 8);
        }
        *(bf16_8*)(&As[row * LDA + c8 * 8]) = val;
    }
    __syncthreads();

    const int wv = tid >> 6, lane = tid & 63;
    const int m0 = wv * 16;
    const int mr = lane & 15, q = lane >> 4;

    f32_4 acc[8];
    #pragma unroll
    for (int nt = 0; nt < 8; ++nt) acc[nt] = (f32_4){0.f, 0.f, 0.f, 0.f};

    #pragma unroll
    for (int ks = 0; ks < 8; ++ks) {
        bf16_8 a = *(const bf16_8*)(&As[(m0 + mr) * LDA + ks * 32 + q * 8]);
        #pragma unroll
        for (int nt = 0; nt < 8; ++nt) {
            bf16_8 b = *(const bf16_8*)(Wt + (nt * 16 + mr) * 256 + ks * 32 + q * 8);
            acc[nt] = __builtin_amdgcn_mfma_f32_16x16x32_bf16(a, b, acc[nt], 0, 0, 0);
        }
    }

    // epilogue: h[row][col] = relu(acc + b1[col]); contract over col with W2 rows.
    float py0[4] = {}, py1[4] = {}, pz0[4] = {}, pz1[4] = {};
    #pragma unroll
    for (int nt = 0; nt < 8; ++nt) {
        int col = nt * 16 + mr;
        float bb  = b1[col];
        float wl0 = W2l[col], wl1 = W2l[128 + col];
        float wr0 = W2r[col], wr1 = W2r[128 + col];
        #pragma unroll
        for (int r = 0; r < 4; ++r) {
            float hv = fmaxf(acc[nt][r] + bb, 0.f);
            py0[r] += hv * wl0; py1[r] += hv * wl1;
            pz0[r] += hv * wr0; pz1[r] += hv * wr1;
        }
    }
    #pragma unroll
    for (int off = 1; off < 16; off <<= 1) {
        #pragma unroll
        for (int r = 0; r < 4; ++r) {
            py0[r] += __shfl_xor(py0[r], off);
            py1[r] += __shfl_xor(py1[r], off);
            pz0[r] += __shfl_xor(pz0[r], off);
            pz1[r] += __shfl_xor(pz1[r], off);
        }
    }
    if (mr < 4) {
        int r = mr;
        int row = i0 + m0 + q * 4 + r;
        if (row < N_NODES) {
            ((float2*)y)[row] = make_float2(py0[r], py1[r]);
            ((float2*)z)[row] = make_float2(pz0[r], pz1[r]);
        }
    }
}

// out = csr-mean(y) + z + b2 ; pull-based, no atomics
__global__ void final_kernel(const int* __restrict__ rowptr, const int* __restrict__ bsum,
                             const int* __restrict__ degc, const int* __restrict__ csr,
                             const float* __restrict__ y, const float* __restrict__ z,
                             const float* __restrict__ b2, float* __restrict__ out) {
    __shared__ int s_scan[256], s_boff[256];
    local_bsum_scan(bsum, s_scan, s_boff);
    int t = blockIdx.x * 256 + threadIdx.x;
    if (t >= 2 * N_NODES) return;
    int node = t >> 1, c = t & 1;
    int beg = rowptr[node] + s_boff[node >> 8], n = degc[node];
    float acc = 0.f;
    for (int j = 0; j < n; ++j) acc += y[csr[beg + j] * 2 + c];
    out[t] = acc / fmaxf((float)n, 1.0f) + z[t] + b2[c];
}

extern "C" void kernel_launch(void* const* d_in, const int* in_sizes, int n_in,
                              void* d_out, int out_size, void* d_ws, size_t ws_size,
                              hipStream_t stream) {
    const float* x   = (const float*)d_in[0];
    const int*   ei  = (const int*)  d_in[1];
    const float* W1l = (const float*)d_in[2];
    const float* W1r = (const float*)d_in[3];
    const float* b1  = (const float*)d_in[4];
    const float* W2l = (const float*)d_in[5];
    const float* W2r = (const float*)d_in[6];
    const float* b2  = (const float*)d_in[7];
    float* out = (float*)d_out;
    const int* src = ei;
    const int* dst = ei + N_EDGES;

    char* ws = (char*)d_ws;
    int*    deg_p    = (int*)   (ws + 0);
    int*    edge_pos = (int*)   (ws + 3200000);
    int*    rowptr   = (int*)   (ws + 6400000);
    int*    degc     = (int*)   (ws + 6600192);
    int*    bsum     = (int*)   (ws + 6800384);
    int*    csr      = (int*)   (ws + 6801408);
    __bf16* xb       = (__bf16*)(ws + 10001408);
    __bf16* aggb     = (__bf16*)(ws + 22801408);
    float*  y        = (float*) (ws + 35601408);
    float*  z        = (float*) (ws + 36001408);
    __bf16* Wt       = (__bf16*)(ws + 36401408);

    hipMemsetAsync(deg_p, 0, 3200000, stream);   // must precede prep_deg atomics
    prep_deg_kernel<<<3253, 256, 0, stream>>>(W1l, W1r, Wt, x, xb, dst, deg_p, edge_pos);
    scan_block_kernel<<<196, 256, 0, stream>>>(deg_p, rowptr, degc, bsum);
    fill_csr_kernel<<<3125, 256, 0, stream>>>(src, dst, rowptr, bsum, edge_pos, csr);
    agg_kernel<<<3125, 256, 0, stream>>>(rowptr, bsum, degc, csr, xb, aggb);
    gemm_fused_kernel<<<782, 256, 0, stream>>>(aggb, xb, Wt, b1, W2l, W2r, y, z);
    final_kernel<<<391, 256, 0, stream>>>(rowptr, bsum, degc, csr, y, z, b2, out);
}